// Round 1
// baseline (959.979 us; speedup 1.0000x reference)
//
#include <hip/hip_runtime.h>
#include <hip/hip_bf16.h>

#define T_TOK 8192
#define DMODEL 1024
#define DFF 2048
#define NEXP 8

typedef __attribute__((ext_vector_type(8))) short short8v;
typedef __attribute__((ext_vector_type(4))) float floatx4;

__device__ __forceinline__ ushort f2bf(float f) {
  union { float f; unsigned u; } v; v.f = f;
  unsigned u = v.u;
  unsigned r = (u + 0x7FFFu + ((u >> 16) & 1u)) >> 16;
  return (ushort)r;
}

// ---------------- zero out + meta ----------------
__global__ void zero_kernel(float* __restrict__ out, int n, int* __restrict__ meta) {
  int i = blockIdx.x * blockDim.x + threadIdx.x;
  for (; i < n; i += gridDim.x * blockDim.x) out[i] = 0.f;
  if (blockIdx.x == 0 && threadIdx.x < 64) meta[threadIdx.x] = 0;
}

// ---------------- gating: logits, top-2, softmax, entropy ----------------
// norm-modulation from the reference is a per-token uniform shift across experts:
// invariant for top-k indices and for softmax(topv) -> skipped entirely.
__global__ __launch_bounds__(256) void gating_kernel(
    const float* __restrict__ x, const float* __restrict__ Wg,
    const float* __restrict__ bg, int* __restrict__ meta,
    int* __restrict__ te, float* __restrict__ tg, float* __restrict__ entOut) {
  __shared__ float wgT[NEXP * DMODEL];
  __shared__ float sbg[NEXP];
  __shared__ float went[4];
  int tid = threadIdx.x;
  for (int idx = tid; idx < NEXP * DMODEL; idx += 256) {
    int d = idx >> 3, e = idx & 7;
    wgT[e * DMODEL + d] = Wg[idx];
  }
  if (tid < NEXP) sbg[tid] = bg[tid];
  __syncthreads();
  int wid = tid >> 6, lane = tid & 63;
  int t = blockIdx.x * 4 + wid;
  float acc[NEXP];
#pragma unroll
  for (int e = 0; e < NEXP; ++e) acc[e] = 0.f;
  const float* xr = x + (long)t * DMODEL;
#pragma unroll
  for (int i = 0; i < DMODEL / 64; ++i) {
    int d = lane + 64 * i;
    float xv = xr[d];
#pragma unroll
    for (int e = 0; e < NEXP; ++e) acc[e] += xv * wgT[e * DMODEL + d];
  }
#pragma unroll
  for (int off = 32; off; off >>= 1)
#pragma unroll
    for (int e = 0; e < NEXP; ++e) acc[e] += __shfl_xor(acc[e], off, 64);
  if (lane == 0) {
    float lg[NEXP];
#pragma unroll
    for (int e = 0; e < NEXP; ++e) lg[e] = acc[e] + sbg[e];
    int e1 = 0; float v1 = lg[0];
#pragma unroll
    for (int e = 1; e < NEXP; ++e) if (lg[e] > v1) { v1 = lg[e]; e1 = e; }
    int e2 = -1; float v2 = -1e30f;
#pragma unroll
    for (int e = 0; e < NEXP; ++e) if (e != e1 && lg[e] > v2) { v2 = lg[e]; e2 = e; }
    float p2 = expf(v2 - v1);
    float s = 1.f + p2;
    float g1 = 1.f / s, g2 = p2 / s;
    float ent = -(g1 * logf(fmaxf(g1, 1e-8f)) + g2 * logf(fmaxf(g2, 1e-8f)));
    atomicAdd(&meta[e1], 1);
    atomicAdd(&meta[e2], 1);
    te[2 * t] = e1; te[2 * t + 1] = e2;
    tg[2 * t] = g1; tg[2 * t + 1] = g2;
    went[wid] = ent;
  }
  __syncthreads();
  if (tid == 0)
    atomicAdd(entOut, (went[0] + went[1] + went[2] + went[3]) * (1.f / T_TOK));
}

// meta layout (ints): counts @0..7, base @16..23, cursor @32..39
__global__ void prefix_kernel(int* __restrict__ meta) {
  if (threadIdx.x == 0) {
    int s = 0;
    for (int e = 0; e < NEXP; ++e) { meta[16 + e] = s; s += meta[e]; meta[32 + e] = 0; }
  }
}

__global__ void scatter_kernel(const int* __restrict__ te, const float* __restrict__ tg,
                               int* __restrict__ meta, int* __restrict__ tok,
                               float* __restrict__ gate) {
  int t = blockIdx.x * blockDim.x + threadIdx.x;
  if (t >= T_TOK) return;
  for (int k = 0; k < 2; ++k) {
    int e = te[2 * t + k];
    int pos = atomicAdd(&meta[32 + e], 1);
    int slot = meta[16 + e] + pos;
    tok[slot] = t;
    gate[slot] = tg[2 * t + k];
  }
}

// ---------------- convert x to bf16 ----------------
__global__ void cvtx_kernel(const float* __restrict__ x, ushort* __restrict__ xb) {
  int i = blockIdx.x * blockDim.x + threadIdx.x;
  if (i >= T_TOK * DMODEL / 8) return;
  const float4* p = (const float4*)(x + (long)i * 8);
  float4 a = p[0], b = p[1];
  short8v v;
  v[0] = (short)f2bf(a.x); v[1] = (short)f2bf(a.y); v[2] = (short)f2bf(a.z); v[3] = (short)f2bf(a.w);
  v[4] = (short)f2bf(b.x); v[5] = (short)f2bf(b.y); v[6] = (short)f2bf(b.z); v[7] = (short)f2bf(b.w);
  *(short8v*)(xb + (long)i * 8) = v;
}

// ---------------- transpose + convert weights: src[e][R][C] f32 -> dst[e][C][R] bf16 ----------------
__global__ __launch_bounds__(256) void tcvt_kernel(const float* __restrict__ src,
                                                   ushort* __restrict__ dst,
                                                   int R, int C) {
  __shared__ ushort tile[64][72];
  int tid = threadIdx.x;
  long eoff = (long)blockIdx.z * R * C;
  int r0 = blockIdx.y * 64, c0 = blockIdx.x * 64;
  int lr = tid >> 4, lc = (tid & 15) * 4;
#pragma unroll
  for (int p = 0; p < 4; ++p) {
    int r = lr + p * 16;
    float4 v = *(const float4*)&src[eoff + (long)(r0 + r) * C + (c0 + lc)];
    tile[r][lc + 0] = f2bf(v.x); tile[r][lc + 1] = f2bf(v.y);
    tile[r][lc + 2] = f2bf(v.z); tile[r][lc + 3] = f2bf(v.w);
  }
  __syncthreads();
  int sr = tid >> 3, sc = (tid & 7) * 8;
#pragma unroll
  for (int p = 0; p < 2; ++p) {
    int c = sr + p * 32;
    short8v v;
#pragma unroll
    for (int j = 0; j < 8; ++j) v[j] = (short)tile[sc + j][c];
    *(short8v*)&dst[eoff + (long)(c0 + c) * R + (r0 + sc)] = v;
  }
}

// ---------------- GEMM1: h = relu(x[tok] @ W1 + b1), bf16 out ----------------
__global__ __launch_bounds__(256) void gemm1_kernel(
    const ushort* __restrict__ xb, const ushort* __restrict__ w1t,
    const float* __restrict__ b1, const int* __restrict__ meta,
    const int* __restrict__ tok, ushort* __restrict__ h) {
  int e = blockIdx.z;
  int cnt = meta[e];
  int m0 = blockIdx.x * 128;
  if (m0 >= cnt) return;
  int n0 = blockIdx.y * 128;
  int bas = meta[16 + e];
  __shared__ ushort As[128 * 64];
  __shared__ ushort Bs[128 * 64];
  __shared__ int toksS[128];
  int tid = threadIdx.x;
  if (tid < 128) {
    int m = m0 + tid;
    toksS[tid] = (m < cnt) ? tok[bas + m] : -1;
  }
  __syncthreads();

  floatx4 acc[4][4];
#pragma unroll
  for (int i = 0; i < 4; ++i)
#pragma unroll
    for (int j = 0; j < 4; ++j) acc[i][j] = (floatx4){0.f, 0.f, 0.f, 0.f};

  int wid = tid >> 6, lane = tid & 63;
  int wm = (wid >> 1) * 64, wn = (wid & 1) * 64;
  int lr = lane & 15, lg = lane >> 4;

  const ushort* w1e = w1t + (long)e * DFF * DMODEL + (long)n0 * DMODEL;

  for (int k0 = 0; k0 < DMODEL; k0 += 64) {
#pragma unroll
    for (int i = 0; i < 4; ++i) {
      int q = tid + 256 * i;
      int row = q >> 3, c8 = q & 7;
      int tk = toksS[row];
      short8v v = {0, 0, 0, 0, 0, 0, 0, 0};
      if (tk >= 0) v = *(const short8v*)(xb + (long)tk * DMODEL + k0 + c8 * 8);
      int byo = (row * 128 + c8 * 16) ^ ((row & 7) << 4);
      *(short8v*)((char*)As + byo) = v;
    }
#pragma unroll
    for (int i = 0; i < 4; ++i) {
      int q = tid + 256 * i;
      int row = q >> 3, c8 = q & 7;
      short8v v = *(const short8v*)(w1e + (long)row * DMODEL + k0 + c8 * 8);
      int byo = (row * 128 + c8 * 16) ^ ((row & 7) << 4);
      *(short8v*)((char*)Bs + byo) = v;
    }
    __syncthreads();
#pragma unroll
    for (int ks = 0; ks < 2; ++ks) {
      short8v af[4], bfv[4];
#pragma unroll
      for (int mi = 0; mi < 4; ++mi) {
        int row = wm + mi * 16 + lr;
        int byo = (row * 128 + ks * 64 + lg * 16) ^ ((row & 7) << 4);
        af[mi] = *(const short8v*)((const char*)As + byo);
      }
#pragma unroll
      for (int ni = 0; ni < 4; ++ni) {
        int row = wn + ni * 16 + lr;
        int byo = (row * 128 + ks * 64 + lg * 16) ^ ((row & 7) << 4);
        bfv[ni] = *(const short8v*)((const char*)Bs + byo);
      }
#pragma unroll
      for (int mi = 0; mi < 4; ++mi)
#pragma unroll
        for (int ni = 0; ni < 4; ++ni)
          acc[mi][ni] = __builtin_amdgcn_mfma_f32_16x16x32_bf16(af[mi], bfv[ni], acc[mi][ni], 0, 0, 0);
    }
    __syncthreads();
  }
#pragma unroll
  for (int mi = 0; mi < 4; ++mi) {
#pragma unroll
    for (int r = 0; r < 4; ++r) {
      int m = m0 + wm + mi * 16 + lg * 4 + r;
      if (m >= cnt) continue;
      long hrow = (long)(bas + m) * DFF;
#pragma unroll
      for (int ni = 0; ni < 4; ++ni) {
        int f = n0 + wn + ni * 16 + lr;
        float v = acc[mi][ni][r] + b1[e * DFF + f];
        v = fmaxf(v, 0.f);
        h[hrow + f] = f2bf(v);
      }
    }
  }
}

// ---------------- GEMM2: out[tok] += gate * (h @ W2 + b2) ----------------
__global__ __launch_bounds__(256) void gemm2_kernel(
    const ushort* __restrict__ h, const ushort* __restrict__ w2t,
    const float* __restrict__ b2, const int* __restrict__ meta,
    const int* __restrict__ tok, const float* __restrict__ gate,
    float* __restrict__ out) {
  int e = blockIdx.z;
  int cnt = meta[e];
  int m0 = blockIdx.x * 128;
  if (m0 >= cnt) return;
  int n0 = blockIdx.y * 128;
  int bas = meta[16 + e];
  __shared__ ushort As[128 * 64];
  __shared__ ushort Bs[128 * 64];
  int tid = threadIdx.x;

  floatx4 acc[4][4];
#pragma unroll
  for (int i = 0; i < 4; ++i)
#pragma unroll
    for (int j = 0; j < 4; ++j) acc[i][j] = (floatx4){0.f, 0.f, 0.f, 0.f};

  int wid = tid >> 6, lane = tid & 63;
  int wm = (wid >> 1) * 64, wn = (wid & 1) * 64;
  int lr = lane & 15, lg = lane >> 4;

  const ushort* w2e = w2t + (long)e * DMODEL * DFF + (long)n0 * DFF;

  for (int k0 = 0; k0 < DFF; k0 += 64) {
#pragma unroll
    for (int i = 0; i < 4; ++i) {
      int q = tid + 256 * i;
      int row = q >> 3, c8 = q & 7;
      int m = m0 + row;
      short8v v = {0, 0, 0, 0, 0, 0, 0, 0};
      if (m < cnt) v = *(const short8v*)(h + (long)(bas + m) * DFF + k0 + c8 * 8);
      int byo = (row * 128 + c8 * 16) ^ ((row & 7) << 4);
      *(short8v*)((char*)As + byo) = v;
    }
#pragma unroll
    for (int i = 0; i < 4; ++i) {
      int q = tid + 256 * i;
      int row = q >> 3, c8 = q & 7;
      short8v v = *(const short8v*)(w2e + (long)row * DFF + k0 + c8 * 8);
      int byo = (row * 128 + c8 * 16) ^ ((row & 7) << 4);
      *(short8v*)((char*)Bs + byo) = v;
    }
    __syncthreads();
#pragma unroll
    for (int ks = 0; ks < 2; ++ks) {
      short8v af[4], bfv[4];
#pragma unroll
      for (int mi = 0; mi < 4; ++mi) {
        int row = wm + mi * 16 + lr;
        int byo = (row * 128 + ks * 64 + lg * 16) ^ ((row & 7) << 4);
        af[mi] = *(const short8v*)((const char*)As + byo);
      }
#pragma unroll
      for (int ni = 0; ni < 4; ++ni) {
        int row = wn + ni * 16 + lr;
        int byo = (row * 128 + ks * 64 + lg * 16) ^ ((row & 7) << 4);
        bfv[ni] = *(const short8v*)((const char*)Bs + byo);
      }
#pragma unroll
      for (int mi = 0; mi < 4; ++mi)
#pragma unroll
        for (int ni = 0; ni < 4; ++ni)
          acc[mi][ni] = __builtin_amdgcn_mfma_f32_16x16x32_bf16(af[mi], bfv[ni], acc[mi][ni], 0, 0, 0);
    }
    __syncthreads();
  }
#pragma unroll
  for (int mi = 0; mi < 4; ++mi) {
#pragma unroll
    for (int r = 0; r < 4; ++r) {
      int m = m0 + wm + mi * 16 + lg * 4 + r;
      if (m >= cnt) continue;
      int slot = bas + m;
      int t = tok[slot];
      float g = gate[slot];
#pragma unroll
      for (int ni = 0; ni < 4; ++ni) {
        int n = n0 + wn + ni * 16 + lr;
        float v = g * (acc[mi][ni][r] + b2[e * DMODEL + n]);
        atomicAdd(&out[(long)t * DMODEL + n], v);
      }
    }
  }
}

extern "C" void kernel_launch(void* const* d_in, const int* in_sizes, int n_in,
                              void* d_out, int out_size, void* d_ws, size_t ws_size,
                              hipStream_t stream) {
  const float* x  = (const float*)d_in[0];
  const float* Wg = (const float*)d_in[1];
  const float* bg = (const float*)d_in[2];
  const float* W1 = (const float*)d_in[3];
  const float* b1 = (const float*)d_in[4];
  const float* W2 = (const float*)d_in[5];
  const float* b2 = (const float*)d_in[6];
  float* out = (float*)d_out;

  char* ws = (char*)d_ws;
  int*    meta = (int*)(ws + 0);            // 1 KB (counts/base/cursor)
  int*    te   = (int*)(ws + 1024);         // 64 KB
  float*  tg   = (float*)(ws + 66560);      // 64 KB
  int*    tokA = (int*)(ws + 132096);       // 64 KB
  float*  gate = (float*)(ws + 197632);     // 64 KB
  ushort* xb   = (ushort*)(ws + 263168);    // 16 MB
  ushort* w1t  = (ushort*)(ws + 17040384);  // 32 MB
  ushort* w2t  = (ushort*)(ws + 50594816);  // 32 MB
  ushort* h    = (ushort*)(ws + 84149248);  // 64 MB  (total ~151.3 MB)

  zero_kernel<<<4096, 256, 0, stream>>>(out, T_TOK * DMODEL + 1, meta);
  gating_kernel<<<T_TOK / 4, 256, 0, stream>>>(x, Wg, bg, meta, te, tg, out + T_TOK * DMODEL);
  prefix_kernel<<<1, 64, 0, stream>>>(meta);
  scatter_kernel<<<T_TOK / 256, 256, 0, stream>>>(te, tg, meta, tokA, gate);
  cvtx_kernel<<<T_TOK * DMODEL / 8 / 256, 256, 0, stream>>>(x, xb);
  tcvt_kernel<<<dim3(DFF / 64, DMODEL / 64, NEXP), 256, 0, stream>>>(W1, w1t, DMODEL, DFF);
  tcvt_kernel<<<dim3(DMODEL / 64, DFF / 64, NEXP), 256, 0, stream>>>(W2, w2t, DFF, DMODEL);
  gemm1_kernel<<<dim3(64, DFF / 128, NEXP), 256, 0, stream>>>(xb, w1t, b1, meta, tokA, h);
  gemm2_kernel<<<dim3(64, DMODEL / 128, NEXP), 256, 0, stream>>>(h, w2t, b2, meta, tokA, gate, out);
}

// Round 2
// 730.966 us; speedup vs baseline: 1.3133x; 1.3133x over previous
//
#include <hip/hip_runtime.h>
#include <hip/hip_bf16.h>

#define T_TOK 8192
#define DMODEL 1024
#define DFF 2048
#define NEXP 8

typedef __attribute__((ext_vector_type(8))) short short8v;
typedef __attribute__((ext_vector_type(4))) float floatx4;
typedef __attribute__((ext_vector_type(4))) ushort ushort4v;

__device__ __forceinline__ ushort f2bf(float f) {
  union { float f; unsigned u; } v; v.f = f;
  unsigned u = v.u;
  unsigned r = (u + 0x7FFFu + ((u >> 16) & 1u)) >> 16;
  return (ushort)r;
}
__device__ __forceinline__ float bf2f(ushort b) {
  union { unsigned u; float f; } v; v.u = ((unsigned)b) << 16;
  return v.f;
}
__device__ __forceinline__ void gload16(const void* g, void* l) {
  __builtin_amdgcn_global_load_lds(
      (const __attribute__((address_space(1))) unsigned int*)g,
      (__attribute__((address_space(3))) unsigned int*)l, 16, 0, 0);
}

// ---------------- init: zero meta + entropy accumulator ----------------
__global__ void init_kernel(int* __restrict__ meta, float* __restrict__ entWs) {
  if (threadIdx.x < 64) meta[threadIdx.x] = 0;
  if (threadIdx.x == 0) *entWs = 0.f;
}

// ---------------- gating: logits, top-2, softmax, entropy; fused x->bf16 ----------------
// norm-modulation in the reference is a per-token uniform shift across experts:
// invariant for top-k indices and softmax(topv) -> skipped entirely.
__global__ __launch_bounds__(256) void gating_kernel(
    const float* __restrict__ x, const float* __restrict__ Wg,
    const float* __restrict__ bg, int* __restrict__ meta,
    int* __restrict__ te, float* __restrict__ tg, float* __restrict__ entWs,
    ushort* __restrict__ xb) {
  __shared__ float wgT[NEXP * DMODEL];
  __shared__ float sbg[NEXP];
  __shared__ float went[4];
  int tid = threadIdx.x;
  for (int idx = tid; idx < NEXP * DMODEL; idx += 256) {
    int d = idx >> 3, e = idx & 7;
    wgT[e * DMODEL + d] = Wg[idx];
  }
  if (tid < NEXP) sbg[tid] = bg[tid];
  __syncthreads();
  int wid = tid >> 6, lane = tid & 63;
  int t = blockIdx.x * 4 + wid;
  float acc[NEXP];
#pragma unroll
  for (int e = 0; e < NEXP; ++e) acc[e] = 0.f;
  const float* xr = x + (long)t * DMODEL;
  ushort* xbr = xb + (long)t * DMODEL;
#pragma unroll
  for (int i = 0; i < DMODEL / 64; ++i) {
    int d = lane + 64 * i;
    float xv = xr[d];
    xbr[d] = f2bf(xv);
#pragma unroll
    for (int e = 0; e < NEXP; ++e) acc[e] += xv * wgT[e * DMODEL + d];
  }
#pragma unroll
  for (int off = 32; off; off >>= 1)
#pragma unroll
    for (int e = 0; e < NEXP; ++e) acc[e] += __shfl_xor(acc[e], off, 64);
  if (lane == 0) {
    float lg[NEXP];
#pragma unroll
    for (int e = 0; e < NEXP; ++e) lg[e] = acc[e] + sbg[e];
    int e1 = 0; float v1 = lg[0];
#pragma unroll
    for (int e = 1; e < NEXP; ++e) if (lg[e] > v1) { v1 = lg[e]; e1 = e; }
    int e2 = -1; float v2 = -1e30f;
#pragma unroll
    for (int e = 0; e < NEXP; ++e) if (e != e1 && lg[e] > v2) { v2 = lg[e]; e2 = e; }
    float p2 = expf(v2 - v1);
    float s = 1.f + p2;
    float g1 = 1.f / s, g2 = p2 / s;
    float ent = -(g1 * logf(fmaxf(g1, 1e-8f)) + g2 * logf(fmaxf(g2, 1e-8f)));
    atomicAdd(&meta[e1], 1);
    atomicAdd(&meta[e2], 1);
    te[2 * t] = e1; te[2 * t + 1] = e2;
    tg[2 * t] = g1; tg[2 * t + 1] = g2;
    went[wid] = ent;
  }
  __syncthreads();
  if (tid == 0)
    atomicAdd(entWs, (went[0] + went[1] + went[2] + went[3]) * (1.f / T_TOK));
}

// meta layout (ints): counts @0..7, base @16..23, cursor @32..39
__global__ void prefix_kernel(int* __restrict__ meta) {
  if (threadIdx.x == 0) {
    int s = 0;
    for (int e = 0; e < NEXP; ++e) { meta[16 + e] = s; s += meta[e]; meta[32 + e] = 0; }
  }
}

__global__ void scatter_kernel(const int* __restrict__ te, const float* __restrict__ tg,
                               int* __restrict__ meta, int* __restrict__ tok,
                               float* __restrict__ gate, int* __restrict__ slotOf) {
  int t = blockIdx.x * blockDim.x + threadIdx.x;
  if (t >= T_TOK) return;
  for (int k = 0; k < 2; ++k) {
    int e = te[2 * t + k];
    int pos = atomicAdd(&meta[32 + e], 1);
    int slot = meta[16 + e] + pos;
    tok[slot] = t;
    gate[slot] = tg[2 * t + k];
    slotOf[2 * t + k] = slot;
  }
}

// ---------------- transpose + convert weights: src[e][R][C] f32 -> dst[e][C][R] bf16 ----------------
__global__ __launch_bounds__(256) void tcvt_kernel(const float* __restrict__ src,
                                                   ushort* __restrict__ dst,
                                                   int R, int C) {
  __shared__ ushort tile[64][72];
  int tid = threadIdx.x;
  long eoff = (long)blockIdx.z * R * C;
  int r0 = blockIdx.y * 64, c0 = blockIdx.x * 64;
  int lr = tid >> 4, lc = (tid & 15) * 4;
#pragma unroll
  for (int p = 0; p < 4; ++p) {
    int r = lr + p * 16;
    float4 v = *(const float4*)&src[eoff + (long)(r0 + r) * C + (c0 + lc)];
    tile[r][lc + 0] = f2bf(v.x); tile[r][lc + 1] = f2bf(v.y);
    tile[r][lc + 2] = f2bf(v.z); tile[r][lc + 3] = f2bf(v.w);
  }
  __syncthreads();
  int sr = tid >> 3, sc = (tid & 7) * 8;
#pragma unroll
  for (int p = 0; p < 2; ++p) {
    int c = sr + p * 32;
    short8v v;
#pragma unroll
    for (int j = 0; j < 8; ++j) v[j] = (short)tile[sc + j][c];
    *(short8v*)&dst[eoff + (long)(c0 + c) * R + (r0 + sc)] = v;
  }
}

// ---------------- GEMM1: h = relu(x[tok] @ W1 + b1), bf16 out ----------------
// m97 structure: linear LDS, global_load_lds width=16, 2 barriers per K-step.
__global__ __launch_bounds__(256) void gemm1_kernel(
    const ushort* __restrict__ xb, const ushort* __restrict__ w1t,
    const float* __restrict__ b1, const int* __restrict__ meta,
    const int* __restrict__ tok, ushort* __restrict__ h) {
  int e = blockIdx.z;
  int cnt = meta[e];
  int m0 = blockIdx.x * 128;
  if (m0 >= cnt) return;
  int n0 = blockIdx.y * 128;
  int bas = meta[16 + e];
  __shared__ ushort As[128 * 64];
  __shared__ ushort Bs[128 * 64];
  int tid = threadIdx.x;

  const ushort* w1e = w1t + (long)e * DFF * DMODEL + (long)n0 * DMODEL;
  const ushort* aSrc[4];
  const ushort* bSrc[4];
#pragma unroll
  for (int i = 0; i < 4; ++i) {
    int q = tid + 256 * i;
    int row = q >> 3, c8 = q & 7;
    int m = m0 + row; if (m >= cnt) m = cnt - 1;
    int tk = tok[bas + m];
    aSrc[i] = xb + (long)tk * DMODEL + c8 * 8;
    bSrc[i] = w1e + (long)row * DMODEL + c8 * 8;
  }

  floatx4 acc[4][4];
#pragma unroll
  for (int i = 0; i < 4; ++i)
#pragma unroll
    for (int j = 0; j < 4; ++j) acc[i][j] = (floatx4){0.f, 0.f, 0.f, 0.f};

  int wid = tid >> 6, lane = tid & 63;
  int wm = (wid >> 1) * 64, wn = (wid & 1) * 64;
  int lr = lane & 15, lg = lane >> 4;

  for (int k0 = 0; k0 < DMODEL; k0 += 64) {
#pragma unroll
    for (int i = 0; i < 4; ++i) {
      int q = tid + 256 * i;
      gload16(aSrc[i] + k0, (char*)As + q * 16);
      gload16(bSrc[i] + k0, (char*)Bs + q * 16);
    }
    __syncthreads();
#pragma unroll
    for (int ks = 0; ks < 2; ++ks) {
      short8v af[4], bfv[4];
#pragma unroll
      for (int mi = 0; mi < 4; ++mi)
        af[mi] = *(const short8v*)((const char*)As + ((wm + mi * 16 + lr) * 128 + ks * 64 + lg * 16));
#pragma unroll
      for (int ni = 0; ni < 4; ++ni)
        bfv[ni] = *(const short8v*)((const char*)Bs + ((wn + ni * 16 + lr) * 128 + ks * 64 + lg * 16));
#pragma unroll
      for (int mi = 0; mi < 4; ++mi)
#pragma unroll
        for (int ni = 0; ni < 4; ++ni)
          acc[mi][ni] = __builtin_amdgcn_mfma_f32_16x16x32_bf16(af[mi], bfv[ni], acc[mi][ni], 0, 0, 0);
    }
    __syncthreads();
  }
#pragma unroll
  for (int mi = 0; mi < 4; ++mi) {
#pragma unroll
    for (int r = 0; r < 4; ++r) {
      int m = m0 + wm + mi * 16 + lg * 4 + r;
      if (m >= cnt) continue;
      long hrow = (long)(bas + m) * DFF;
#pragma unroll
      for (int ni = 0; ni < 4; ++ni) {
        int f = n0 + wn + ni * 16 + lr;
        float v = acc[mi][ni][r] + b1[e * DFF + f];
        v = fmaxf(v, 0.f);
        h[hrow + f] = f2bf(v);
      }
    }
  }
}

// ---------------- GEMM2: y[slot] = gate * (h[slot] @ W2 + b2), bf16, NO atomics ----------------
__global__ __launch_bounds__(256) void gemm2_kernel(
    const ushort* __restrict__ h, const ushort* __restrict__ w2t,
    const float* __restrict__ b2, const int* __restrict__ meta,
    const float* __restrict__ gate, ushort* __restrict__ y) {
  int e = blockIdx.z;
  int cnt = meta[e];
  int m0 = blockIdx.x * 128;
  if (m0 >= cnt) return;
  int n0 = blockIdx.y * 128;
  int bas = meta[16 + e];
  __shared__ ushort As[128 * 64];
  __shared__ ushort Bs[128 * 64];
  int tid = threadIdx.x;

  const ushort* w2e = w2t + (long)e * DMODEL * DFF + (long)n0 * DFF;
  const ushort* aSrc[4];
  const ushort* bSrc[4];
#pragma unroll
  for (int i = 0; i < 4; ++i) {
    int q = tid + 256 * i;
    int row = q >> 3, c8 = q & 7;
    int m = m0 + row; if (m >= cnt) m = cnt - 1;
    aSrc[i] = h + (long)(bas + m) * DFF + c8 * 8;
    bSrc[i] = w2e + (long)row * DFF + c8 * 8;
  }

  floatx4 acc[4][4];
#pragma unroll
  for (int i = 0; i < 4; ++i)
#pragma unroll
    for (int j = 0; j < 4; ++j) acc[i][j] = (floatx4){0.f, 0.f, 0.f, 0.f};

  int wid = tid >> 6, lane = tid & 63;
  int wm = (wid >> 1) * 64, wn = (wid & 1) * 64;
  int lr = lane & 15, lg = lane >> 4;

  for (int k0 = 0; k0 < DFF; k0 += 64) {
#pragma unroll
    for (int i = 0; i < 4; ++i) {
      int q = tid + 256 * i;
      gload16(aSrc[i] + k0, (char*)As + q * 16);
      gload16(bSrc[i] + k0, (char*)Bs + q * 16);
    }
    __syncthreads();
#pragma unroll
    for (int ks = 0; ks < 2; ++ks) {
      short8v af[4], bfv[4];
#pragma unroll
      for (int mi = 0; mi < 4; ++mi)
        af[mi] = *(const short8v*)((const char*)As + ((wm + mi * 16 + lr) * 128 + ks * 64 + lg * 16));
#pragma unroll
      for (int ni = 0; ni < 4; ++ni)
        bfv[ni] = *(const short8v*)((const char*)Bs + ((wn + ni * 16 + lr) * 128 + ks * 64 + lg * 16));
#pragma unroll
      for (int mi = 0; mi < 4; ++mi)
#pragma unroll
        for (int ni = 0; ni < 4; ++ni)
          acc[mi][ni] = __builtin_amdgcn_mfma_f32_16x16x32_bf16(af[mi], bfv[ni], acc[mi][ni], 0, 0, 0);
    }
    __syncthreads();
  }
#pragma unroll
  for (int mi = 0; mi < 4; ++mi) {
#pragma unroll
    for (int r = 0; r < 4; ++r) {
      int m = m0 + wm + mi * 16 + lg * 4 + r;
      if (m >= cnt) continue;
      int slot = bas + m;
      float g = gate[slot];
      ushort* yr = y + (long)slot * DMODEL;
#pragma unroll
      for (int ni = 0; ni < 4; ++ni) {
        int n = n0 + wn + ni * 16 + lr;
        float v = g * (acc[mi][ni][r] + b2[e * DMODEL + n]);
        yr[n] = f2bf(v);
      }
    }
  }
}

// ---------------- combine: out[t] = y[slot1] + y[slot2]; entropy copy ----------------
__global__ __launch_bounds__(256) void combine_kernel(
    const ushort* __restrict__ y, const int* __restrict__ slotOf,
    const float* __restrict__ entWs, float* __restrict__ out) {
  int t = blockIdx.x;
  int s1 = slotOf[2 * t], s2 = slotOf[2 * t + 1];
  int d = threadIdx.x * 4;
  ushort4v a = *(const ushort4v*)&y[(long)s1 * DMODEL + d];
  ushort4v b = *(const ushort4v*)&y[(long)s2 * DMODEL + d];
  float4 r;
  r.x = bf2f(a[0]) + bf2f(b[0]);
  r.y = bf2f(a[1]) + bf2f(b[1]);
  r.z = bf2f(a[2]) + bf2f(b[2]);
  r.w = bf2f(a[3]) + bf2f(b[3]);
  *(float4*)&out[(long)t * DMODEL + d] = r;
  if (t == 0 && threadIdx.x == 0) out[(long)T_TOK * DMODEL] = *entWs;
}

extern "C" void kernel_launch(void* const* d_in, const int* in_sizes, int n_in,
                              void* d_out, int out_size, void* d_ws, size_t ws_size,
                              hipStream_t stream) {
  const float* x  = (const float*)d_in[0];
  const float* Wg = (const float*)d_in[1];
  const float* bg = (const float*)d_in[2];
  const float* W1 = (const float*)d_in[3];
  const float* b1 = (const float*)d_in[4];
  const float* W2 = (const float*)d_in[5];
  const float* b2 = (const float*)d_in[6];
  float* out = (float*)d_out;

  char* ws = (char*)d_ws;
  int*    meta   = (int*)(ws + 0);            // 256B (counts/base/cursor)
  float*  entWs  = (float*)(ws + 256);
  int*    te     = (int*)(ws + 1024);         // 64 KB
  float*  tg     = (float*)(ws + 66560);      // 64 KB
  int*    tokA   = (int*)(ws + 132096);       // 64 KB
  float*  gate   = (float*)(ws + 197632);     // 64 KB
  int*    slotOf = (int*)(ws + 263168);       // 64 KB
  ushort* xb     = (ushort*)(ws + 328704);    // 16 MB
  ushort* w1t    = (ushort*)(ws + 17105920);  // 32 MB  (dead after gemm1 -> reused as y)
  ushort* w2t    = (ushort*)(ws + 50660352);  // 32 MB
  ushort* h      = (ushort*)(ws + 84214784);  // 64 MB  (total ~151.3 MB, same as proven)
  ushort* y      = w1t;                       // alias: w1t consumed by gemm1 before gemm2 writes y

  init_kernel<<<1, 64, 0, stream>>>(meta, entWs);
  gating_kernel<<<T_TOK / 4, 256, 0, stream>>>(x, Wg, bg, meta, te, tg, entWs, xb);
  prefix_kernel<<<1, 1, 0, stream>>>(meta);
  scatter_kernel<<<T_TOK / 256, 256, 0, stream>>>(te, tg, meta, tokA, gate, slotOf);
  tcvt_kernel<<<dim3(DFF / 64, DMODEL / 64, NEXP), 256, 0, stream>>>(W1, w1t, DMODEL, DFF);
  tcvt_kernel<<<dim3(DMODEL / 64, DFF / 64, NEXP), 256, 0, stream>>>(W2, w2t, DFF, DMODEL);
  gemm1_kernel<<<dim3(64, DFF / 128, NEXP), 256, 0, stream>>>(xb, w1t, b1, meta, tokA, h);
  gemm2_kernel<<<dim3(64, DMODEL / 128, NEXP), 256, 0, stream>>>(h, w2t, b2, meta, gate, y);
  combine_kernel<<<T_TOK, 256, 0, stream>>>(y, slotOf, entWs, out);
}